// Round 2
// baseline (440.926 us; speedup 1.0000x reference)
//
#include <hip/hip_runtime.h>

// Problem constants: N=8, H=32, L=512, S=512, MAX_SPATIAL=100
#define NN 8
#define HH 32
#define LL 512
#define SS 512
#define MAXP 100

// L*S/4 = 65536 float4-units per (n,h) slice
#define LS4 65536

// Native vector types so __builtin_nontemporal_load/store accept them
typedef float f32x4 __attribute__((ext_vector_type(4)));
typedef int   i32x4 __attribute__((ext_vector_type(4)));

__global__ __launch_bounds__(256) void gpe_kernel(
    const float* __restrict__ QK,
    const int*   __restrict__ pos,
    const float* __restrict__ emb,
    float*       __restrict__ out)
{
    // Table staged transposed: tbl[h*MAXP + p] = emb[p*H + h], row p==0 zeroed.
    // Within a wave h is uniform, p ~random in [0,100) -> banks spread.
    __shared__ float tbl[HH * MAXP];
    const int tid = threadIdx.x;
    for (int idx = tid; idx < HH * MAXP; idx += 256) {
        const int p = idx >> 5;          // / HH  (HH == 32)
        const int h = idx & (HH - 1);
        tbl[h * MAXP + p] = (p == 0) ? 0.0f : emb[p * HH + h];
    }
    __syncthreads();

    // One thread per 4 consecutive s of one (n,l); loops over all H heads so
    // pos is read exactly once from HBM.
    const int vecId = blockIdx.x * 256 + tid;      // 0 .. N*L*S/4 - 1
    const int n   = vecId >> 16;                   // / LS4
    const int ls4 = vecId & (LS4 - 1);

    const i32x4 p4 = ((const i32x4*)pos)[vecId];

    const f32x4* __restrict__ qk4  = (const f32x4*)QK;
    f32x4*       __restrict__ out4 = (f32x4*)out;

    // base index in float4 units; max = 7*32*65536 + 65535 < 2^24
    int idx4 = n * (HH * LS4) + ls4;

    // unroll 8: eight independent load->add->store chains in flight per thread.
    // nontemporal: QK/out are 536 MB of single-use stream - bypass L2 so pos
    // and the emb table stay cache-resident.
#pragma unroll 8
    for (int h = 0; h < HH; ++h, idx4 += LS4) {
        const float* th = &tbl[h * MAXP];
        f32x4 q = __builtin_nontemporal_load(&qk4[idx4]);
        q.x += th[p4.x];
        q.y += th[p4.y];
        q.z += th[p4.z];
        q.w += th[p4.w];
        __builtin_nontemporal_store(q, &out4[idx4]);
    }
}

extern "C" void kernel_launch(void* const* d_in, const int* in_sizes, int n_in,
                              void* d_out, int out_size, void* d_ws, size_t ws_size,
                              hipStream_t stream) {
    const float* QK  = (const float*)d_in[0];
    const int*   pos = (const int*)d_in[1];
    const float* emb = (const float*)d_in[2];
    float*       out = (float*)d_out;

    const int total_vec = (NN * LL * SS) / 4;   // 524288 threads
    const int block = 256;
    const int grid = total_vec / block;          // 2048 blocks
    gpe_kernel<<<grid, block, 0, stream>>>(QK, pos, emb, out);
}